// Round 4
// baseline (263.434 us; speedup 1.0000x reference)
//
#include <hip/hip_runtime.h>

typedef unsigned short u16;
typedef unsigned int u32;
typedef unsigned long long u64;

typedef __attribute__((ext_vector_type(8))) short short8;
typedef __attribute__((ext_vector_type(2))) float f32x2;
typedef __attribute__((ext_vector_type(4))) float f32x4;
typedef __attribute__((ext_vector_type(16))) float f32x16;
typedef __attribute__((ext_vector_type(4))) u32 u32x4;

#define DEVI static __device__ __forceinline__

DEVI u16 f2bf(float f) {
  u32 u = __float_as_uint(f);
  return (u16)((u + 0x7fffu + ((u >> 16) & 1u)) >> 16);
}

DEVI u64 pack4f(float a, float b, float c, float d) {
  return (u64)f2bf(a) | ((u64)f2bf(b) << 16) | ((u64)f2bf(c) << 32) |
         ((u64)f2bf(d) << 48);
}

DEVI u32 cvtpk_bf16(float lo, float hi) {
  u32 r;
  asm("v_cvt_pk_bf16_f32 %0, %1, %2" : "=v"(r) : "v"(lo), "v"(hi));
  return r;
}

DEVI void gld_lds16(const void* g, void* l) {
  __builtin_amdgcn_global_load_lds(
      (const __attribute__((address_space(1))) void*)g,
      (__attribute__((address_space(3))) void*)l, 16, 0, 0);
}

DEVI f32x4 mfma16(short8 a, short8 b, f32x4 c) {
  return __builtin_amdgcn_mfma_f32_16x16x32_bf16(a, b, c, 0, 0, 0);
}

DEVI f32x16 mfma32(short8 a, short8 b, f32x16 c) {
  return __builtin_amdgcn_mfma_f32_32x32x16_bf16(a, b, c, 0, 0, 0);
}

DEVI f32x4 zero4() {
  f32x4 z = {0.f, 0.f, 0.f, 0.f};
  return z;
}

// ---------------------------------------------------------------- fp32->bf16
__global__ __launch_bounds__(256) void cvt_bf16(const float* __restrict__ s,
                                                u16* __restrict__ d, int n4) {
  int i = blockIdx.x * 256 + threadIdx.x;
  int stride = gridDim.x * 256;
  for (; i < n4; i += stride) {
    f32x4 v = ((const f32x4*)s)[i];
    ((u64*)d)[i] = pack4f(v.x, v.y, v.z, v.w);
  }
}

// ------------------------------------------------- GEMM1: qkv = W_qkv @ x^T
__global__ __launch_bounds__(256, 2) void gemm_qkv(
    const u16* __restrict__ W, const u16* __restrict__ X, u16* __restrict__ Q,
    u16* __restrict__ K, u16* __restrict__ V) {
  __shared__ alignas(16) char smem[36864];
  u16* As = (u16*)smem;
  u16* Bs = (u16*)(smem + 8192);

  const int tid = threadIdx.x;
  const int wid = tid >> 6, lane = tid & 63;
  const int lr = lane & 15, lg = lane >> 4;
  const int wr = wid >> 1, wc = wid & 1;
  const int f_base = blockIdx.y * 128;
  const int m_base = blockIdx.x * 128;

  f32x4 acc[4][4];
#pragma unroll
  for (int i = 0; i < 4; ++i)
#pragma unroll
    for (int j = 0; j < 4; ++j) acc[i][j] = zero4();

  const int srow = tid >> 2;
  const int scol = (tid & 3) << 4;
  const char* Ag = (const char*)(W + (u64)f_base * 1024) + (u64)srow * 2048 + scol;
  const char* Bg = (const char*)(X + (u64)m_base * 1024) + (u64)srow * 2048 + scol;
  char* Asd = (char*)As + tid * 16;
  char* Bsd = (char*)Bs + tid * 16;

  for (int kt = 0; kt < 32; ++kt) {
    const int kb = kt * 64;
    gld_lds16(Ag + kb, Asd);
    gld_lds16(Ag + kb + 64 * 2048, Asd + 4096);
    gld_lds16(Bg + kb, Bsd);
    gld_lds16(Bg + kb + 64 * 2048, Bsd + 4096);
    __syncthreads();
    short8 af[4], bf[4];
#pragma unroll
    for (int mi = 0; mi < 4; ++mi)
      af[mi] = *(const short8*)(As + (wr * 64 + mi * 16 + lr) * 32 + lg * 8);
#pragma unroll
    for (int ni = 0; ni < 4; ++ni)
      bf[ni] = *(const short8*)(Bs + (wc * 64 + ni * 16 + lr) * 32 + lg * 8);
#pragma unroll
    for (int mi = 0; mi < 4; ++mi)
#pragma unroll
      for (int ni = 0; ni < 4; ++ni)
        acc[mi][ni] = mfma16(af[mi], bf[ni], acc[mi][ni]);
    __syncthreads();
  }

  const int f0 = f_base + wr * 64;
  const int m0 = m_base + wc * 64;
  const int b = m0 >> 10, n0 = m0 & 1023;
  const int which = f0 >> 10;
  const int h = (f0 & 1023) >> 6;
  const int bh = b * 16 + h;

  if (which < 2) {
    // fold softmax scale * log2(e) into Q
    const float qs = (which == 0) ? (0.125f * 1.44269504088896f) : 1.f;
    u16* Ob = (u16*)smem + wid * (64 * 72);
#pragma unroll
    for (int mi = 0; mi < 4; ++mi)
#pragma unroll
      for (int ni = 0; ni < 4; ++ni) {
        int ml = ni * 16 + lr;
        int fl = mi * 16 + lg * 4;
        f32x4 a = acc[mi][ni] * qs;
        *(u64*)(Ob + ml * 72 + fl) = pack4f(a.x, a.y, a.z, a.w);
      }
    __syncthreads();
    u16* dst = (which ? K : Q) + ((u64)bh * 1024 + n0) * 64;
#pragma unroll
    for (int it = 0; it < 8; ++it) {
      int ml = it * 8 + (lane >> 3);
      int c = lane & 7;
      *(short8*)(dst + ml * 64 + c * 8) = *(const short8*)(Ob + ml * 72 + c * 8);
    }
  } else {
    // V^T with keys permuted within each 16-group: n' = swap bits2<->3 of
    // (n&15).  Makes attention's natural per-lane P order match the V
    // fragment read directly (no cross-lane exchange in the hot loop).
    u16* dst = V + (u64)bh * 64 * 1024;
    const int lrp = (lr & 3) | ((lr & 4) << 1) | ((lr & 8) >> 1);
#pragma unroll
    for (int mi = 0; mi < 4; ++mi) {
      int d0 = mi * 16 + lg * 4;
#pragma unroll
      for (int ni = 0; ni < 4; ++ni) {
        int n = n0 + ni * 16 + lrp;
#pragma unroll
        for (int r = 0; r < 4; ++r)
          dst[(u64)(d0 + r) * 1024 + n] = f2bf(acc[mi][ni][r]);
      }
    }
  }
}

// ------------------------------------------------------------ flash attention
// 32x32x16 structure, 4 waves x 32 q; lane owns one q row (softmax in-reg).
// K/V chunk-col LDS (conflict-free, no swizzle); V key-permuted at source so
// P needs no cross-lane exchange.  Optimistic exp with overflow-guarded
// recovery replaces the per-iter max tree.  f32x2 math for pk-packed VALU.
__global__ __launch_bounds__(256, 4) void attn_fwd(const u16* __restrict__ Q,
                                                   const u16* __restrict__ K,
                                                   const u16* __restrict__ V,
                                                   u16* __restrict__ AO) {
  __shared__ alignas(16) u16 Ks[2][4096];
  __shared__ alignas(16) u16 Vs[2][4096];

  const int tid = threadIdx.x;
  const int wid = tid >> 6, lane = tid & 63;
  const int l31 = lane & 31, hi = lane >> 5;

  const int i = blockIdx.x;
  const int qblk = (i >> 3) & 7;
  const int bh = (i & 7) * 16 + (i >> 6);

  const u64 kvbase = (u64)bh * (1024 * 64);
  const int q0w = qblk * 128 + wid * 32;

  short8 qf[4];
  {
    const char* qrow = (const char*)(Q + kvbase + (u64)(q0w + l31) * 64);
#pragma unroll
    for (int ss = 0; ss < 4; ++ss)
      qf[ss] = *(const short8*)(qrow + 32 * ss + 16 * hi);
  }

  float m_run = -INFINITY, l_run = 0.f;
  f32x16 o0 = {0}, o1 = {0};

  const int sr = tid & 63, scc = tid >> 6;
  const char* kgb = (const char*)(K + kvbase);
  const char* vgb = (const char*)(V + kvbase);

#define STAGE(buf, kt)                                                       \
  do {                                                                       \
    const char* kg = kgb + (u64)(kt) * 8192;                                 \
    const char* vg = vgb + (kt) * 128;                                       \
    gld_lds16(kg + sr * 128 + scc * 16, (char*)Ks[buf] + tid * 16);          \
    gld_lds16(kg + sr * 128 + (scc + 4) * 16,                                \
              (char*)Ks[buf] + (tid + 256) * 16);                            \
    gld_lds16(vg + sr * 2048 + scc * 16, (char*)Vs[buf] + tid * 16);         \
    gld_lds16(vg + sr * 2048 + (scc + 4) * 16,                               \
              (char*)Vs[buf] + (tid + 256) * 16);                            \
  } while (0)

  STAGE(0, 0);

  struct P8 { f32x2 v[8]; };

  for (int kt = 0; kt < 16; ++kt) {
    const int cur = kt & 1;
    if (kt + 1 < 16) {
      STAGE(cur ^ 1, kt + 1);
      asm volatile("s_waitcnt vmcnt(4)" ::: "memory");
    } else {
      asm volatile("s_waitcnt vmcnt(0)" ::: "memory");
    }
    __builtin_amdgcn_s_barrier();
    asm volatile("" ::: "memory");

    const char* Kc = (const char*)Ks[cur];
    const char* Vc = (const char*)Vs[cur];

    // ---- S^T = K * Q^T
    f32x16 s0 = {0}, s1 = {0};
    __builtin_amdgcn_s_setprio(1);
#pragma unroll
    for (int ss = 0; ss < 4; ++ss) {
      const int ch = (2 * ss + hi) << 10;
      short8 kf0 = *(const short8*)(Kc + ch + (l31 << 4));
      short8 kf1 = *(const short8*)(Kc + ch + ((32 + l31) << 4));
      s0 = mfma32(kf0, qf[ss], s0);
      s1 = mfma32(kf1, qf[ss], s1);
    }
    __builtin_amdgcn_s_setprio(0);

    // ---- softmax: optimistic exp with stale max; guarded recovery
    P8 a0 = __builtin_bit_cast(P8, s0);
    P8 a1 = __builtin_bit_cast(P8, s1);
    P8 e0, e1;
    float psum;
#define DO_EXPSUM()                                                          \
  do {                                                                       \
    f32x2 mneg = {-m_run, -m_run};                                           \
    _Pragma("unroll") for (int j = 0; j < 8; ++j) {                          \
      f32x2 t0 = a0.v[j] + mneg;                                             \
      f32x2 t1 = a1.v[j] + mneg;                                             \
      e0.v[j].x = exp2f(t0.x);                                               \
      e0.v[j].y = exp2f(t0.y);                                               \
      e1.v[j].x = exp2f(t1.x);                                               \
      e1.v[j].y = exp2f(t1.y);                                               \
    }                                                                        \
    f32x2 u[4];                                                              \
    _Pragma("unroll") for (int j = 0; j < 4; ++j) u[j] =                     \
        (e0.v[j] + e0.v[j + 4]) + (e1.v[j] + e1.v[j + 4]);                   \
    u[0] += u[2];                                                            \
    u[1] += u[3];                                                            \
    u[0] += u[1];                                                            \
    psum = u[0].x + u[0].y;                                                  \
  } while (0)
    DO_EXPSUM();
    if (__any(!(psum < 0x1p24f))) {
      // rare: true max, rescale state, recompute (handles first tile too)
      float pm = -INFINITY;
#pragma unroll
      for (int j = 0; j < 8; ++j)
        pm = fmaxf(pm, fmaxf(fmaxf(a0.v[j].x, a0.v[j].y),
                             fmaxf(a1.v[j].x, a1.v[j].y)));
      pm = fmaxf(pm, __shfl_xor(pm, 32));
      float m_new = fmaxf(m_run, pm);
      float alpha = exp2f(m_run - m_new);  // exp2(-inf) = 0 on first tile
      l_run *= alpha;
      o0 *= alpha;
      o1 *= alpha;
      m_run = m_new;
      DO_EXPSUM();
    }
#undef DO_EXPSUM
    psum += __shfl_xor(psum, 32);
    l_run += psum;

    // ---- PV: P fragments are lane-natural (V pre-permuted at source)
    __builtin_amdgcn_s_setprio(1);
#pragma unroll
    for (int s = 0; s < 4; ++s) {
      const P8& ee = (s < 2) ? e0 : e1;
      const int base = (s & 1) * 4;
      u32x4 pw;
      pw.x = cvtpk_bf16(ee.v[base + 0].x, ee.v[base + 0].y);
      pw.y = cvtpk_bf16(ee.v[base + 1].x, ee.v[base + 1].y);
      pw.z = cvtpk_bf16(ee.v[base + 2].x, ee.v[base + 2].y);
      pw.w = cvtpk_bf16(ee.v[base + 3].x, ee.v[base + 3].y);
      short8 pf = __builtin_bit_cast(short8, pw);

      const int ch = (2 * s + hi) << 10;
      short8 vf0 = *(const short8*)(Vc + ch + (l31 << 4));
      short8 vf1 = *(const short8*)(Vc + ch + ((32 + l31) << 4));
      o0 = mfma32(vf0, pf, o0);
      o1 = mfma32(vf1, pf, o1);
    }
    __builtin_amdgcn_s_setprio(0);

    asm volatile("" ::: "memory");
    __builtin_amdgcn_s_barrier();
    asm volatile("" ::: "memory");
  }
#undef STAGE

  // ---- epilogue: normalize, per-wave LDS transpose, coalesced store
  __syncthreads();
  float inv_l = 1.f / l_run;
  u16* Ob = (u16*)((char*)Ks + wid * 4096);
#pragma unroll
  for (int j4 = 0; j4 < 4; ++j4) {
    u64 wa = (u64)cvtpk_bf16(o0[4 * j4] * inv_l, o0[4 * j4 + 1] * inv_l) |
             ((u64)cvtpk_bf16(o0[4 * j4 + 2] * inv_l, o0[4 * j4 + 3] * inv_l)
              << 32);
    u64 wb = (u64)cvtpk_bf16(o1[4 * j4] * inv_l, o1[4 * j4 + 1] * inv_l) |
             ((u64)cvtpk_bf16(o1[4 * j4 + 2] * inv_l, o1[4 * j4 + 3] * inv_l)
              << 32);
    *(u64*)(Ob + l31 * 64 + (((j4 ^ (l31 & 7)) << 4) + 8 * hi) / 2) = wa;
    *(u64*)(Ob + l31 * 64 + ((((4 + j4) ^ (l31 & 7)) << 4) + 8 * hi) / 2) = wb;
  }
  const int b = bh >> 4, h = bh & 15;
#pragma unroll
  for (int it = 0; it < 4; ++it) {
    int qr = it * 8 + (lane >> 3);
    int cd = lane & 7;
    short8 vvv = *(const short8*)(Ob + qr * 64 + (((cd ^ (qr & 7)) << 4) / 2));
    u16* dst = AO + ((u64)(b * 1024 + q0w + qr) * 1024 + h * 64 + cd * 8);
    *(short8*)dst = vvv;
  }
}

// ----------------------------------------------- GEMM2: out = AO @ Wp^T + b
__global__ __launch_bounds__(256, 2) void gemm_proj(const u16* __restrict__ W,
                                                    const u16* __restrict__ X,
                                                    const float* __restrict__ bias,
                                                    float* __restrict__ Out) {
  __shared__ alignas(16) char smem[16384];
  u16* As = (u16*)smem;
  u16* Bs = (u16*)(smem + 8192);

  const int tid = threadIdx.x;
  const int wid = tid >> 6, lane = tid & 63;
  const int lr = lane & 15, lg = lane >> 4;
  const int wr = wid >> 1, wc = wid & 1;
  const int f_base = blockIdx.y * 128;
  const int m_base = blockIdx.x * 128;

  f32x4 acc[4][4];
#pragma unroll
  for (int i = 0; i < 4; ++i)
#pragma unroll
    for (int j = 0; j < 4; ++j) acc[i][j] = zero4();

  const int srow = tid >> 2;
  const int scol = (tid & 3) << 4;
  const char* Ag = (const char*)(W + (u64)f_base * 1024) + (u64)srow * 2048 + scol;
  const char* Bg = (const char*)(X + (u64)m_base * 1024) + (u64)srow * 2048 + scol;
  char* Asd = (char*)As + tid * 16;
  char* Bsd = (char*)Bs + tid * 16;

  for (int kt = 0; kt < 32; ++kt) {
    const int kb = kt * 64;
    gld_lds16(Ag + kb, Asd);
    gld_lds16(Ag + kb + 64 * 2048, Asd + 4096);
    gld_lds16(Bg + kb, Bsd);
    gld_lds16(Bg + kb + 64 * 2048, Bsd + 4096);
    __syncthreads();
    short8 af[4], bf[4];
#pragma unroll
    for (int mi = 0; mi < 4; ++mi)
      af[mi] = *(const short8*)(As + (wr * 64 + mi * 16 + lr) * 32 + lg * 8);
#pragma unroll
    for (int ni = 0; ni < 4; ++ni)
      bf[ni] = *(const short8*)(Bs + (wc * 64 + ni * 16 + lr) * 32 + lg * 8);
#pragma unroll
    for (int mi = 0; mi < 4; ++mi)
#pragma unroll
      for (int ni = 0; ni < 4; ++ni)
        acc[mi][ni] = mfma16(af[mi], bf[ni], acc[mi][ni]);
    __syncthreads();
  }

  const int f0 = f_base + wr * 64;
  const int m0 = m_base + wc * 64;
#pragma unroll
  for (int mi = 0; mi < 4; ++mi) {
    int f = f0 + mi * 16 + lg * 4;
    f32x4 bv = *(const f32x4*)(bias + f);
#pragma unroll
    for (int ni = 0; ni < 4; ++ni) {
      int m = m0 + ni * 16 + lr;
      f32x4 o = acc[mi][ni] + bv;
      *(f32x4*)(Out + (u64)m * 1024 + f) = o;
    }
  }
}

// ---------------------------------------------------------------------------
extern "C" void kernel_launch(void* const* d_in, const int* in_sizes, int n_in,
                              void* d_out, int out_size, void* d_ws,
                              size_t ws_size, hipStream_t stream) {
  const float* x = (const float*)d_in[0];
  const float* w_qkv = (const float*)d_in[1];
  const float* w_proj = (const float*)d_in[2];
  const float* b_proj = (const float*)d_in[3];
  float* out = (float*)d_out;
  char* ws = (char*)d_ws;

  u16* xb = (u16*)(ws);                  // 16 MB  [8192,1024] bf16
  u16* wqb = (u16*)(ws + 16777216);      // 6 MB   [3072,1024] bf16
  u16* wpb = (u16*)(ws + 23068672);      // 2 MB   [1024,1024] bf16
  u16* qb = (u16*)(ws + 25165824);       // 16 MB  [B,H,N,D] bf16 (pre-scaled)
  u16* kb = (u16*)(ws + 41943040);       // 16 MB  [B,H,N,D] bf16
  u16* vt = (u16*)(ws + 58720256);       // 16 MB  [B,H,D,N] bf16 (key-permuted)
  u16* ao = (u16*)(ws + 75497472);       // 16 MB  [8192,1024] bf16

  hipLaunchKernelGGL(cvt_bf16, dim3(2048), dim3(256), 0, stream, x, xb,
                     8192 * 1024 / 4);
  hipLaunchKernelGGL(cvt_bf16, dim3(1024), dim3(256), 0, stream, w_qkv, wqb,
                     3072 * 1024 / 4);
  hipLaunchKernelGGL(cvt_bf16, dim3(512), dim3(256), 0, stream, w_proj, wpb,
                     1024 * 1024 / 4);
  hipLaunchKernelGGL(gemm_qkv, dim3(64, 24), dim3(256), 0, stream, wqb, xb, qb,
                     kb, vt);
  hipLaunchKernelGGL(attn_fwd, dim3(1024), dim3(256), 0, stream, qb, kb, vt,
                     ao);
  hipLaunchKernelGGL(gemm_proj, dim3(64, 8), dim3(256), 0, stream, wpb, ao,
                     b_proj, out);
}

// Round 5
// 156.076 us; speedup vs baseline: 1.6879x; 1.6879x over previous
//
#include <hip/hip_runtime.h>

typedef unsigned short u16;
typedef unsigned int u32;
typedef unsigned long long u64;

typedef __attribute__((ext_vector_type(8))) short short8;
typedef __attribute__((ext_vector_type(4))) float f32x4;
typedef __attribute__((ext_vector_type(16))) float f32x16;
typedef __attribute__((ext_vector_type(4))) u32 u32x4;

#define DEVI static __device__ __forceinline__

DEVI u16 f2bf(float f) {
  u32 u = __float_as_uint(f);
  return (u16)((u + 0x7fffu + ((u >> 16) & 1u)) >> 16);
}

DEVI u64 pack4f(float a, float b, float c, float d) {
  return (u64)f2bf(a) | ((u64)f2bf(b) << 16) | ((u64)f2bf(c) << 32) |
         ((u64)f2bf(d) << 48);
}

DEVI u32 cvtpk_bf16(float lo, float hi) {
  u32 r;
  asm("v_cvt_pk_bf16_f32 %0, %1, %2" : "=v"(r) : "v"(lo), "v"(hi));
  return r;
}

DEVI void gld_lds16(const void* g, void* l) {
  __builtin_amdgcn_global_load_lds(
      (const __attribute__((address_space(1))) void*)g,
      (__attribute__((address_space(3))) void*)l, 16, 0, 0);
}

DEVI f32x4 mfma16(short8 a, short8 b, f32x4 c) {
  return __builtin_amdgcn_mfma_f32_16x16x32_bf16(a, b, c, 0, 0, 0);
}

DEVI f32x16 mfma32(short8 a, short8 b, f32x16 c) {
  return __builtin_amdgcn_mfma_f32_32x32x16_bf16(a, b, c, 0, 0, 0);
}

DEVI f32x4 zero4() {
  f32x4 z = {0.f, 0.f, 0.f, 0.f};
  return z;
}

// ---------------------------------------------------------------- fp32->bf16
__global__ __launch_bounds__(256) void cvt_bf16(const float* __restrict__ s,
                                                u16* __restrict__ d, int n4) {
  int i = blockIdx.x * 256 + threadIdx.x;
  int stride = gridDim.x * 256;
  for (; i < n4; i += stride) {
    f32x4 v = ((const f32x4*)s)[i];
    ((u64*)d)[i] = pack4f(v.x, v.y, v.z, v.w);
  }
}

// ------------------------------------------------- GEMM1: qkv = W_qkv @ x^T
// BK=64 (halves barrier/drain events vs BK=32).  LDS tiles [128][64el],
// XOR-swizzled chunks (pre-swizzled global source + XOR'd ds_read; LDS
// dest stays linear for global_load_lds) -> 2-way conflicts only.
__global__ __launch_bounds__(256, 2) void gemm_qkv(
    const u16* __restrict__ W, const u16* __restrict__ X, u16* __restrict__ Q,
    u16* __restrict__ K, u16* __restrict__ V) {
  __shared__ alignas(16) char smem[36864];
  u16* As = (u16*)smem;                // 16 KB [128][64]
  u16* Bs = (u16*)(smem + 16384);      // 16 KB

  const int tid = threadIdx.x;
  const int wid = tid >> 6, lane = tid & 63;
  const int lr = lane & 15, lg = lane >> 4;
  const int wr = wid >> 1, wc = wid & 1;
  const int f_base = blockIdx.y * 128;
  const int m_base = blockIdx.x * 128;

  f32x4 acc[4][4];
#pragma unroll
  for (int i = 0; i < 4; ++i)
#pragma unroll
    for (int j = 0; j < 4; ++j) acc[i][j] = zero4();

  // staging: call i covers tile rows [i*32, i*32+32); thread -> row,chunk
  const int grow = tid >> 3;           // 0..31 row within 32-row slab
  const int gch = tid & 7;             // 16B chunk 0..7 within 128B row
  const int gsw = gch ^ (grow & 7);    // pre-swizzled source chunk
  const u64 soff = (u64)grow * 2048 + gsw * 16;
  const char* Ag = (const char*)(W + (u64)f_base * 1024) + soff;
  const char* Bg = (const char*)(X + (u64)m_base * 1024) + soff;
  char* Asd = (char*)As + tid * 16;
  char* Bsd = (char*)Bs + tid * 16;

  // fragment read offsets (loop-invariant): row = wr*64+mi*16+lr,
  // chunk j = kk*4+lg read at j^(row&7)
  int aoff[2][4], boff[2][4];
#pragma unroll
  for (int kk = 0; kk < 2; ++kk)
#pragma unroll
    for (int i = 0; i < 4; ++i) {
      int ra = wr * 64 + i * 16 + lr;
      int rb = wc * 64 + i * 16 + lr;
      aoff[kk][i] = ra * 128 + (((kk * 4 + lg) ^ (ra & 7)) << 4);
      boff[kk][i] = rb * 128 + (((kk * 4 + lg) ^ (rb & 7)) << 4);
    }

  for (int kt = 0; kt < 16; ++kt) {
    const u64 kb = (u64)kt * 128;  // bytes into K
#pragma unroll
    for (int i = 0; i < 4; ++i) {
      gld_lds16(Ag + kb + (u64)i * 65536, Asd + i * 4096);
      gld_lds16(Bg + kb + (u64)i * 65536, Bsd + i * 4096);
    }
    __syncthreads();
    short8 af[2][4], bf[2][4];
#pragma unroll
    for (int kk = 0; kk < 2; ++kk) {
#pragma unroll
      for (int i = 0; i < 4; ++i) {
        af[kk][i] = *(const short8*)((const char*)As + aoff[kk][i]);
        bf[kk][i] = *(const short8*)((const char*)Bs + boff[kk][i]);
      }
    }
    __builtin_amdgcn_s_setprio(1);
#pragma unroll
    for (int kk = 0; kk < 2; ++kk)
#pragma unroll
      for (int mi = 0; mi < 4; ++mi)
#pragma unroll
        for (int ni = 0; ni < 4; ++ni)
          acc[mi][ni] = mfma16(af[kk][mi], bf[kk][ni], acc[mi][ni]);
    __builtin_amdgcn_s_setprio(0);
    __syncthreads();
  }

  const int f0 = f_base + wr * 64;
  const int m0 = m_base + wc * 64;
  const int b = m0 >> 10, n0 = m0 & 1023;
  const int which = f0 >> 10;
  const int h = (f0 & 1023) >> 6;
  const int bh = b * 16 + h;

  if (which < 2) {
    // fold softmax scale * log2(e) into Q
    const float qs = (which == 0) ? (0.125f * 1.44269504088896f) : 1.f;
    u16* Ob = (u16*)smem + wid * (64 * 72);
#pragma unroll
    for (int mi = 0; mi < 4; ++mi)
#pragma unroll
      for (int ni = 0; ni < 4; ++ni) {
        int ml = ni * 16 + lr;
        int fl = mi * 16 + lg * 4;
        f32x4 a = acc[mi][ni] * qs;
        *(u64*)(Ob + ml * 72 + fl) = pack4f(a.x, a.y, a.z, a.w);
      }
    __syncthreads();
    u16* dst = (which ? K : Q) + ((u64)bh * 1024 + n0) * 64;
#pragma unroll
    for (int it = 0; it < 8; ++it) {
      int ml = it * 8 + (lane >> 3);
      int c = lane & 7;
      *(short8*)(dst + ml * 64 + c * 8) = *(const short8*)(Ob + ml * 72 + c * 8);
    }
  } else {
    // V^T with keys permuted within each 16-group (swap bits 2<->3 of n&15):
    // attention's natural per-lane P order then matches the V fragment read
    // directly (no cross-lane exchange in the hot loop).  Verified R4.
    u16* dst = V + (u64)bh * 64 * 1024;
    const int lrp = (lr & 3) | ((lr & 4) << 1) | ((lr & 8) >> 1);
#pragma unroll
    for (int mi = 0; mi < 4; ++mi) {
      int d0 = mi * 16 + lg * 4;
#pragma unroll
      for (int ni = 0; ni < 4; ++ni) {
        int n = n0 + ni * 16 + lrp;
#pragma unroll
        for (int r = 0; r < 4; ++r)
          dst[(u64)(d0 + r) * 1024 + n] = f2bf(acc[mi][ni][r]);
      }
    }
  }
}

// ------------------------------------------------------------ flash attention
// 32x32x16 structure, 4 waves x 32 q; lane owns one q row (softmax in-reg,
// in-place exp -> no extra live state, no spills).  K/V chunk-col LDS
// (conflict-free); V key-permuted at source so P needs no cross-lane
// exchange.  Defer-max (T13), double-buffered staging with counted vmcnt.
__global__ __launch_bounds__(256, 4) void attn_fwd(const u16* __restrict__ Q,
                                                   const u16* __restrict__ K,
                                                   const u16* __restrict__ V,
                                                   u16* __restrict__ AO) {
  __shared__ alignas(16) u16 Ks[2][4096];
  __shared__ alignas(16) u16 Vs[2][4096];

  const int tid = threadIdx.x;
  const int wid = tid >> 6, lane = tid & 63;
  const int l31 = lane & 31, hi = lane >> 5;

  const int i = blockIdx.x;
  const int qblk = (i >> 3) & 7;
  const int bh = (i & 7) * 16 + (i >> 6);

  const u64 kvbase = (u64)bh * (1024 * 64);
  const int q0w = qblk * 128 + wid * 32;

  short8 qf[4];
  {
    const char* qrow = (const char*)(Q + kvbase + (u64)(q0w + l31) * 64);
#pragma unroll
    for (int ss = 0; ss < 4; ++ss)
      qf[ss] = *(const short8*)(qrow + 32 * ss + 16 * hi);
  }

  float m_run = -INFINITY, l_run = 0.f;
  f32x16 o0 = {0}, o1 = {0};

  const int sr = tid & 63, scc = tid >> 6;
  const char* kgb = (const char*)(K + kvbase);
  const char* vgb = (const char*)(V + kvbase);

#define STAGE(buf, kt)                                                       \
  do {                                                                       \
    const char* kg = kgb + (u64)(kt) * 8192;                                 \
    const char* vg = vgb + (kt) * 128;                                       \
    gld_lds16(kg + sr * 128 + scc * 16, (char*)Ks[buf] + tid * 16);          \
    gld_lds16(kg + sr * 128 + (scc + 4) * 16,                                \
              (char*)Ks[buf] + (tid + 256) * 16);                            \
    gld_lds16(vg + sr * 2048 + scc * 16, (char*)Vs[buf] + tid * 16);         \
    gld_lds16(vg + sr * 2048 + (scc + 4) * 16,                               \
              (char*)Vs[buf] + (tid + 256) * 16);                            \
  } while (0)

  STAGE(0, 0);

  for (int kt = 0; kt < 16; ++kt) {
    const int cur = kt & 1;
    if (kt + 1 < 16) {
      STAGE(cur ^ 1, kt + 1);
      asm volatile("s_waitcnt vmcnt(4)" ::: "memory");
    } else {
      asm volatile("s_waitcnt vmcnt(0)" ::: "memory");
    }
    __builtin_amdgcn_s_barrier();
    asm volatile("" ::: "memory");

    const char* Kc = (const char*)Ks[cur];
    const char* Vc = (const char*)Vs[cur];

    // ---- S^T = K * Q^T
    f32x16 s0 = {0}, s1 = {0};
    __builtin_amdgcn_s_setprio(1);
#pragma unroll
    for (int ss = 0; ss < 4; ++ss) {
      const int ch = (2 * ss + hi) << 10;
      short8 kf0 = *(const short8*)(Kc + ch + (l31 << 4));
      short8 kf1 = *(const short8*)(Kc + ch + ((32 + l31) << 4));
      s0 = mfma32(kf0, qf[ss], s0);
      s1 = mfma32(kf1, qf[ss], s1);
    }
    __builtin_amdgcn_s_setprio(0);

    // ---- softmax, lane-local; defer-max; exp in place (low reg pressure)
    float t[16];
#pragma unroll
    for (int j = 0; j < 16; ++j) t[j] = fmaxf(s0[j], s1[j]);
#pragma unroll
    for (int j = 0; j < 8; ++j) t[j] = fmaxf(t[j], t[j + 8]);
#pragma unroll
    for (int j = 0; j < 4; ++j) t[j] = fmaxf(t[j], t[j + 4]);
    float pm = fmaxf(fmaxf(t[0], t[1]), fmaxf(t[2], t[3]));
    pm = fmaxf(pm, __shfl_xor(pm, 32));

    if (__any(pm - m_run > 8.f)) {
      float m_new = fmaxf(m_run, pm);
      float alpha = exp2f(m_run - m_new);  // exp2(-inf)=0 on first tile
      l_run *= alpha;
      o0 *= alpha;
      o1 *= alpha;
      m_run = m_new;
    }

#pragma unroll
    for (int j = 0; j < 16; ++j) {
      s0[j] = exp2f(s0[j] - m_run);
      s1[j] = exp2f(s1[j] - m_run);
    }
    float u[8];
#pragma unroll
    for (int j = 0; j < 8; ++j) u[j] = (s0[j] + s0[j + 8]) + (s1[j] + s1[j + 8]);
#pragma unroll
    for (int j = 0; j < 4; ++j) u[j] += u[j + 4];
    float psum = (u[0] + u[1]) + (u[2] + u[3]);
    psum += __shfl_xor(psum, 32);
    l_run += psum;

    // ---- PV: P is lane-natural (V pre-permuted at source) — verified R4
    __builtin_amdgcn_s_setprio(1);
#pragma unroll
    for (int s = 0; s < 4; ++s) {
      const int off = (s & 1) * 8;
      u32x4 pw;
      if (s < 2) {
        pw.x = cvtpk_bf16(s0[off + 0], s0[off + 1]);
        pw.y = cvtpk_bf16(s0[off + 2], s0[off + 3]);
        pw.z = cvtpk_bf16(s0[off + 4], s0[off + 5]);
        pw.w = cvtpk_bf16(s0[off + 6], s0[off + 7]);
      } else {
        pw.x = cvtpk_bf16(s1[off + 0], s1[off + 1]);
        pw.y = cvtpk_bf16(s1[off + 2], s1[off + 3]);
        pw.z = cvtpk_bf16(s1[off + 4], s1[off + 5]);
        pw.w = cvtpk_bf16(s1[off + 6], s1[off + 7]);
      }
      short8 pf = __builtin_bit_cast(short8, pw);

      const int ch = (2 * s + hi) << 10;
      short8 vf0 = *(const short8*)(Vc + ch + (l31 << 4));
      short8 vf1 = *(const short8*)(Vc + ch + ((32 + l31) << 4));
      o0 = mfma32(vf0, pf, o0);
      o1 = mfma32(vf1, pf, o1);
    }
    __builtin_amdgcn_s_setprio(0);

    asm volatile("" ::: "memory");
    __builtin_amdgcn_s_barrier();
    asm volatile("" ::: "memory");
  }
#undef STAGE

  // ---- epilogue: normalize, per-wave LDS transpose, coalesced store
  __syncthreads();
  float inv_l = 1.f / l_run;
  u16* Ob = (u16*)((char*)Ks + wid * 4096);
#pragma unroll
  for (int j4 = 0; j4 < 4; ++j4) {
    u64 wa = (u64)cvtpk_bf16(o0[4 * j4] * inv_l, o0[4 * j4 + 1] * inv_l) |
             ((u64)cvtpk_bf16(o0[4 * j4 + 2] * inv_l, o0[4 * j4 + 3] * inv_l)
              << 32);
    u64 wb = (u64)cvtpk_bf16(o1[4 * j4] * inv_l, o1[4 * j4 + 1] * inv_l) |
             ((u64)cvtpk_bf16(o1[4 * j4 + 2] * inv_l, o1[4 * j4 + 3] * inv_l)
              << 32);
    *(u64*)(Ob + l31 * 64 + (((j4 ^ (l31 & 7)) << 4) + 8 * hi) / 2) = wa;
    *(u64*)(Ob + l31 * 64 + ((((4 + j4) ^ (l31 & 7)) << 4) + 8 * hi) / 2) = wb;
  }
  const int b = bh >> 4, h = bh & 15;
#pragma unroll
  for (int it = 0; it < 4; ++it) {
    int qr = it * 8 + (lane >> 3);
    int cd = lane & 7;
    short8 vvv = *(const short8*)(Ob + qr * 64 + (((cd ^ (qr & 7)) << 4) / 2));
    u16* dst = AO + ((u64)(b * 1024 + q0w + qr) * 1024 + h * 64 + cd * 8);
    *(short8*)dst = vvv;
  }
}

// ----------------------------------------------- GEMM2: out = AO @ Wp^T + b
// Same BK=64 + swizzle structure as gemm_qkv.
__global__ __launch_bounds__(256, 2) void gemm_proj(const u16* __restrict__ W,
                                                    const u16* __restrict__ X,
                                                    const float* __restrict__ bias,
                                                    float* __restrict__ Out) {
  __shared__ alignas(16) char smem[32768];
  u16* As = (u16*)smem;
  u16* Bs = (u16*)(smem + 16384);

  const int tid = threadIdx.x;
  const int wid = tid >> 6, lane = tid & 63;
  const int lr = lane & 15, lg = lane >> 4;
  const int wr = wid >> 1, wc = wid & 1;
  const int f_base = blockIdx.y * 128;
  const int m_base = blockIdx.x * 128;

  f32x4 acc[4][4];
#pragma unroll
  for (int i = 0; i < 4; ++i)
#pragma unroll
    for (int j = 0; j < 4; ++j) acc[i][j] = zero4();

  const int grow = tid >> 3;
  const int gch = tid & 7;
  const int gsw = gch ^ (grow & 7);
  const u64 soff = (u64)grow * 2048 + gsw * 16;
  const char* Ag = (const char*)(W + (u64)f_base * 1024) + soff;
  const char* Bg = (const char*)(X + (u64)m_base * 1024) + soff;
  char* Asd = (char*)As + tid * 16;
  char* Bsd = (char*)Bs + tid * 16;

  int aoff[2][4], boff[2][4];
#pragma unroll
  for (int kk = 0; kk < 2; ++kk)
#pragma unroll
    for (int i = 0; i < 4; ++i) {
      int ra = wr * 64 + i * 16 + lr;
      int rb = wc * 64 + i * 16 + lr;
      aoff[kk][i] = ra * 128 + (((kk * 4 + lg) ^ (ra & 7)) << 4);
      boff[kk][i] = rb * 128 + (((kk * 4 + lg) ^ (rb & 7)) << 4);
    }

  for (int kt = 0; kt < 16; ++kt) {
    const u64 kb = (u64)kt * 128;
#pragma unroll
    for (int i = 0; i < 4; ++i) {
      gld_lds16(Ag + kb + (u64)i * 65536, Asd + i * 4096);
      gld_lds16(Bg + kb + (u64)i * 65536, Bsd + i * 4096);
    }
    __syncthreads();
    short8 af[2][4], bf[2][4];
#pragma unroll
    for (int kk = 0; kk < 2; ++kk) {
#pragma unroll
      for (int i = 0; i < 4; ++i) {
        af[kk][i] = *(const short8*)((const char*)As + aoff[kk][i]);
        bf[kk][i] = *(const short8*)((const char*)Bs + boff[kk][i]);
      }
    }
    __builtin_amdgcn_s_setprio(1);
#pragma unroll
    for (int kk = 0; kk < 2; ++kk)
#pragma unroll
      for (int mi = 0; mi < 4; ++mi)
#pragma unroll
        for (int ni = 0; ni < 4; ++ni)
          acc[mi][ni] = mfma16(af[kk][mi], bf[kk][ni], acc[mi][ni]);
    __builtin_amdgcn_s_setprio(0);
    __syncthreads();
  }

  const int f0 = f_base + wr * 64;
  const int m0 = m_base + wc * 64;
#pragma unroll
  for (int mi = 0; mi < 4; ++mi) {
    int f = f0 + mi * 16 + lg * 4;
    f32x4 bv = *(const f32x4*)(bias + f);
#pragma unroll
    for (int ni = 0; ni < 4; ++ni) {
      int m = m0 + ni * 16 + lr;
      f32x4 o = acc[mi][ni] + bv;
      *(f32x4*)(Out + (u64)m * 1024 + f) = o;
    }
  }
}

// ---------------------------------------------------------------------------
extern "C" void kernel_launch(void* const* d_in, const int* in_sizes, int n_in,
                              void* d_out, int out_size, void* d_ws,
                              size_t ws_size, hipStream_t stream) {
  const float* x = (const float*)d_in[0];
  const float* w_qkv = (const float*)d_in[1];
  const float* w_proj = (const float*)d_in[2];
  const float* b_proj = (const float*)d_in[3];
  float* out = (float*)d_out;
  char* ws = (char*)d_ws;

  u16* xb = (u16*)(ws);                  // 16 MB  [8192,1024] bf16
  u16* wqb = (u16*)(ws + 16777216);      // 6 MB   [3072,1024] bf16
  u16* wpb = (u16*)(ws + 23068672);      // 2 MB   [1024,1024] bf16
  u16* qb = (u16*)(ws + 25165824);       // 16 MB  [B,H,N,D] bf16 (pre-scaled)
  u16* kb = (u16*)(ws + 41943040);       // 16 MB  [B,H,N,D] bf16
  u16* vt = (u16*)(ws + 58720256);       // 16 MB  [B,H,D,N] bf16 (key-permuted)
  u16* ao = (u16*)(ws + 75497472);       // 16 MB  [8192,1024] bf16

  hipLaunchKernelGGL(cvt_bf16, dim3(2048), dim3(256), 0, stream, x, xb,
                     8192 * 1024 / 4);
  hipLaunchKernelGGL(cvt_bf16, dim3(1024), dim3(256), 0, stream, w_qkv, wqb,
                     3072 * 1024 / 4);
  hipLaunchKernelGGL(cvt_bf16, dim3(512), dim3(256), 0, stream, w_proj, wpb,
                     1024 * 1024 / 4);
  hipLaunchKernelGGL(gemm_qkv, dim3(64, 24), dim3(256), 0, stream, wqb, xb, qb,
                     kb, vt);
  hipLaunchKernelGGL(attn_fwd, dim3(1024), dim3(256), 0, stream, qb, kb, vt,
                     ao);
  hipLaunchKernelGGL(gemm_proj, dim3(64, 8), dim3(256), 0, stream, wpb, ao,
                     b_proj, out);
}